// Round 4
// baseline (37.024 us; speedup 1.0000x reference)
//
#include <hip/hip_runtime.h>
#include <hip/hip_bf16.h>
#include <stdint.h>

// Problem constants (fixed by reference): B=2048, D=256, Vg=2, Vt=4 (only j<2 used), T=0.2
#define TB 2048
#define TD 256

typedef __attribute__((ext_vector_type(8)))  short        bf16x8;
typedef __attribute__((ext_vector_type(16))) float        f32x16;
typedef __attribute__((ext_vector_type(4)))  unsigned int u32x4;

#define SQRT5 2.23606797749979f   // fold sqrt(1/T)=sqrt(5) into BOTH normalized operands

// ---------------------------------------------------------------------------
// Kernel 1: normalize rows (l2, eps=1e-12), scale by sqrt(5), cast to bf16.
// r < 4096: projected rows (b*2+i); else predicted rows (b,j<2) -> qn[b*2+j].
// ---------------------------------------------------------------------------
__global__ __launch_bounds__(256) void nnclr_prep(const float* __restrict__ proj,
                                                  const float* __restrict__ pred,
                                                  unsigned short* __restrict__ pn,
                                                  unsigned short* __restrict__ qn) {
    const int r = blockIdx.x;       // 0..8191
    const int t = threadIdx.x;      // 0..255 == element index in row
    const float* src;
    unsigned short* dst;
    if (r < 4096) {
        src = proj + (size_t)r * TD;
        dst = pn  + (size_t)r * TD;
    } else {
        const int r2 = r - 4096;           // b*2 + j
        const int b = r2 >> 1, j = r2 & 1;
        src = pred + ((size_t)b * 4 + j) * TD;
        dst = qn   + (size_t)r2 * TD;
    }
    float x = src[t];
    float ss = x * x;
    #pragma unroll
    for (int m = 1; m < 64; m <<= 1) ss += __shfl_xor(ss, m, 64);
    __shared__ float wsum[4];
    if ((t & 63) == 0) wsum[t >> 6] = ss;
    __syncthreads();
    const float tot = wsum[0] + wsum[1] + wsum[2] + wsum[3];
    const float scale = SQRT5 / fmaxf(sqrtf(tot), 1e-12f);
    const float y = x * scale;
    // bf16 round-to-nearest-even
    const unsigned int bits = __float_as_uint(y);
    dst[t] = (unsigned short)((bits + 0x7FFFu + ((bits >> 16) & 1u)) >> 16);
}

// ---------------------------------------------------------------------------
// Kernel 2: per (pair, c-half, 32-row block): logits tile via MFMA, fixed-max
// (m=5, provable bound: |p.q|<=1 => |logit|<=5) sum-of-exp + diagonal pick.
// grid = (64 rowblocks, 2 chalf, 4 pairs), 256 threads (4 waves).
// LDS = 16KB pA + 64KB qB = 80KB exactly -> 2 blocks/CU.
// ---------------------------------------------------------------------------
__global__ __launch_bounds__(256, 2) void nnclr_main(const unsigned short* __restrict__ pn,
                                                     const unsigned short* __restrict__ qn,
                                                     float* __restrict__ sPart,  // [4][2048][2]
                                                     float* __restrict__ dPart)  // [4][2048][2]
{
    const int rb   = blockIdx.x;          // 0..63
    const int ch   = blockIdx.y;          // 0..1
    const int pair = blockIdx.z;          // 0..3 : i = pair>>1, j = pair&1
    const int pi = pair >> 1, pj = pair & 1;
    const int tid  = threadIdx.x;
    const int lane = tid & 63, wave = tid >> 6;
    const int b0 = rb * 32;               // global row base
    const int c0base = ch * 1024;         // global col base for this block

    __shared__ __align__(16) unsigned char lds[81920];
    unsigned char* pA = lds;              // [32 rows][512B], granule-swizzled
    unsigned char* qB = lds + 16384;      // [128 rows][512B], granule-swizzled

    // ---- stage pA (32 rows x 32 granules of 16B), swizzle: slot = g ^ (row&7)
    #pragma unroll
    for (int p = 0; p < 4; ++p) {
        const int idx = p * 256 + tid;
        const int r = idx >> 5, sl = idx & 31;
        const unsigned short* gp = pn + (((size_t)(b0 + r) * 2 + pi) * TD) + sl * 8;
        u32x4 v = *(const u32x4*)gp;
        *(u32x4*)(pA + r * 512 + (((sl ^ (r & 7)) << 4))) = v;
    }
    __syncthreads();

    // ---- hoist all A fragments (16 k-steps of K=16) into registers
    // A layout (32x32x16): row = lane&31, k = 8*(lane>>5)+e  -> granule 2*ks + hk
    bf16x8 aF[16];
    {
        const int row = lane & 31;
        const int hk  = lane >> 5;
        #pragma unroll
        for (int ks = 0; ks < 16; ++ks) {
            const int g = ks * 2 + hk;
            aF[ks] = *(const bf16x8*)(pA + row * 512 + (((g ^ (row & 7)) << 4)));
        }
    }

    float sAcc[16], dAcc[16];
    #pragma unroll
    for (int r = 0; r < 16; ++r) { sAcc[r] = 0.f; dAcc[r] = 0.f; }

    const int wc = wave * 32;             // wave's col slice within the 128-col tile
    const int hk = lane >> 5;
    const int brow = wc + (lane & 31);    // B-frag row in qB (= col of output)

    u32x4 stg[16];
    // load tile 0
    #pragma unroll
    for (int p = 0; p < 16; ++p) {
        const int idx = p * 256 + tid;
        const int r = idx >> 5, sl = idx & 31;
        stg[p] = *(const u32x4*)(qn + (((size_t)(c0base + r) * 2 + pj) * TD) + sl * 8);
    }
    #pragma unroll
    for (int p = 0; p < 16; ++p) {
        const int idx = p * 256 + tid;
        const int r = idx >> 5, sl = idx & 31;
        *(u32x4*)(qB + r * 512 + (((sl ^ (r & 7)) << 4))) = stg[p];
    }
    __syncthreads();

    for (int t = 0; t < 8; ++t) {
        // issue global loads for next tile (overlap with compute)
        if (t + 1 < 8) {
            const int c0 = c0base + (t + 1) * 128;
            #pragma unroll
            for (int p = 0; p < 16; ++p) {
                const int idx = p * 256 + tid;
                const int r = idx >> 5, sl = idx & 31;
                stg[p] = *(const u32x4*)(qn + (((size_t)(c0 + r) * 2 + pj) * TD) + sl * 8);
            }
        }
        // ---- 16 k-steps MFMA, two interleaved acc chains
        f32x16 acc0, acc1;
        #pragma unroll
        for (int r = 0; r < 16; ++r) { acc0[r] = 0.f; acc1[r] = 0.f; }
        #pragma unroll
        for (int ks = 0; ks < 16; ks += 2) {
            const bf16x8 bf0 = *(const bf16x8*)(qB + brow * 512 + ((((ks * 2 + hk) ^ (brow & 7)) << 4)));
            acc0 = __builtin_amdgcn_mfma_f32_32x32x16_bf16(aF[ks], bf0, acc0, 0, 0, 0);
            const bf16x8 bf1 = *(const bf16x8*)(qB + brow * 512 + (((((ks + 1) * 2 + hk) ^ (brow & 7)) << 4)));
            acc1 = __builtin_amdgcn_mfma_f32_32x32x16_bf16(aF[ks + 1], bf1, acc1, 0, 0, 0);
        }
        // ---- fixed-max (m=5) sum-of-exp + diag pick
        // C layout (32x32): col = lane&31, row_local = (r&3) + 8*(r>>2) + 4*hk
        const bool hasDiag = (c0base + t * 128 + wc == b0);   // wave-uniform
        #pragma unroll
        for (int r = 0; r < 16; ++r) {
            const float v = acc0[r] + acc1[r];                 // = logits value
            sAcc[r] += __expf(v - 5.0f);
            if (hasDiag) {
                const int rowl = (r & 3) + 8 * (r >> 2) + 4 * hk;
                if ((lane & 31) == rowl) dAcc[r] += v;
            }
        }
        __syncthreads();
        if (t + 1 < 8) {
            #pragma unroll
            for (int p = 0; p < 16; ++p) {
                const int idx = p * 256 + tid;
                const int r = idx >> 5, sl = idx & 31;
                *(u32x4*)(qB + r * 512 + (((sl ^ (r & 7)) << 4))) = stg[p];
            }
        }
        __syncthreads();
    }

    // ---- reduce s,d over the 32 lanes of each half-wave (cols of this wave)
    #pragma unroll
    for (int r = 0; r < 16; ++r) {
        float s = sAcc[r], d = dAcc[r];
        #pragma unroll
        for (int m = 1; m < 32; m <<= 1) {
            s += __shfl_xor(s, m, 64);
            d += __shfl_xor(d, m, 64);
        }
        sAcc[r] = s; dAcc[r] = d;
    }
    // ---- combine across waves via LDS (reuse pA region; all compute done)
    float* sArr = (float*)lds;            // [4 waves][32 rows]
    float* dArr = (float*)(lds + 512);
    if ((lane & 31) == 0) {
        #pragma unroll
        for (int r = 0; r < 16; ++r) {
            const int rowl = (r & 3) + 8 * (r >> 2) + 4 * hk;
            sArr[wave * 32 + rowl] = sAcc[r];
            dArr[wave * 32 + rowl] = dAcc[r];
        }
    }
    __syncthreads();
    if (tid < 32) {
        float s = 0.f, d = 0.f;
        #pragma unroll
        for (int w = 0; w < 4; ++w) { s += sArr[w * 32 + tid]; d += dArr[w * 32 + tid]; }
        const int b = b0 + tid;
        sPart[((size_t)pair * TB + b) * 2 + ch] = s;
        dPart[((size_t)pair * TB + b) * 2 + ch] = d;
    }
}

// ---------------------------------------------------------------------------
// Kernel 3: combine halves, lse - diag = 5 + ln(s) - d, reduce to 3 outputs.
// ---------------------------------------------------------------------------
__global__ __launch_bounds__(1024) void nnclr_final(const float* __restrict__ sPart,
                                                    const float* __restrict__ dPart,
                                                    float* __restrict__ out) {
    const int tid = threadIdx.x;
    float acc[4] = {0.f, 0.f, 0.f, 0.f};
    #pragma unroll
    for (int k = 0; k < 8; ++k) {
        const int row = tid + k * 1024;   // pair*2048 + b ; pair = k>>1 (constant)
        const float s = sPart[row * 2] + sPart[row * 2 + 1];
        const float d = dPart[row * 2] + dPart[row * 2 + 1];
        acc[k >> 1] += 5.0f + logf(s) - d;
    }
    __shared__ float red[16][4];
    const int lane = tid & 63, wave = tid >> 6;
    #pragma unroll
    for (int p = 0; p < 4; ++p) {
        #pragma unroll
        for (int m = 1; m < 64; m <<= 1) acc[p] += __shfl_xor(acc[p], m, 64);
    }
    if (lane == 0) {
        #pragma unroll
        for (int p = 0; p < 4; ++p) red[wave][p] = acc[p];
    }
    __syncthreads();
    if (tid == 0) {
        float L[4];
        #pragma unroll
        for (int p = 0; p < 4; ++p) {
            float a = 0.f;
            for (int w = 0; w < 16; ++w) a += red[w][p];
            L[p] = a / (float)TB;         // mean over b
        }
        const float gs = L[1] + L[2];                 // L[0][1] + L[1][0]
        const float ls = L[0] + L[1] + L[2] + L[3];   // all four (Vl==Vg==2)
        out[0] = (gs + ls) / 6.0f;        // total
        out[1] = gs * 0.5f;               // global_loss
        out[2] = ls * 0.25f;              // local_loss
    }
}

extern "C" void kernel_launch(void* const* d_in, const int* in_sizes, int n_in,
                              void* d_out, int out_size, void* d_ws, size_t ws_size,
                              hipStream_t stream) {
    const float* projected = (const float*)d_in[0];   // [2048][2][256] f32
    const float* predicted = (const float*)d_in[1];   // [2048][4][256] f32

    unsigned short* pn = (unsigned short*)d_ws;                         // 2 MB bf16
    unsigned short* qn = pn + (size_t)TB * 2 * TD;                      // 2 MB bf16
    float* sPart = (float*)((char*)d_ws + 4u * 1024u * 1024u);          // 64 KB
    float* dPart = sPart + (size_t)4 * TB * 2;                          // 64 KB
    float* out = (float*)d_out;

    nnclr_prep<<<8192, 256, 0, stream>>>(projected, predicted, pn, qn);
    dim3 grid(64, 2, 4);
    nnclr_main<<<grid, 256, 0, stream>>>(pn, qn, sPart, dPart);
    nnclr_final<<<1, 1024, 0, stream>>>(sPart, dPart, out);
}

// Round 5
// 31.588 us; speedup vs baseline: 1.1721x; 1.1721x over previous
//
#include <hip/hip_runtime.h>
#include <hip/hip_bf16.h>
#include <stdint.h>

// Problem constants (fixed by reference): B=2048, D=256, Vg=2, Vt=4 (only j<2 used), T=0.2
#define TB 2048
#define TD 256

typedef __attribute__((ext_vector_type(8)))  short        bf16x8;
typedef __attribute__((ext_vector_type(16))) float        f32x16;

#define SQRT5 2.23606797749979f   // fold sqrt(1/T)=sqrt(5) into BOTH normalized operands

// ---------------------------------------------------------------------------
// Kernel 1: normalize rows, scale by sqrt(5), cast bf16, and write in MFMA
// fragment order: pq2[v][grp][g][col] of 16B granules, where v in {p_i0,p_i1,
// q_j0,q_j1}, grp = b>>5, col = b&31, g = k granule (k in [8g,8g+8)).
// One block per (grp, v): 32 rows staged in LDS, transposed write.
// ---------------------------------------------------------------------------
__global__ __launch_bounds__(256) void nnclr_prep(const float* __restrict__ proj,
                                                  const float* __restrict__ pred,
                                                  unsigned short* __restrict__ pq2) {
    const int grp = blockIdx.x;      // 0..63
    const int v   = blockIdx.y;      // 0..3
    const int t   = threadIdx.x;     // 0..255

    __shared__ float rowbuf[32][260];   // +4 pad: phase-2/norm reads ~2-way max
    __shared__ float scales[32];

    // phase 1: bulk-load 32 rows (all loads independent -> deep in flight)
    float x[32];
    #pragma unroll
    for (int m = 0; m < 32; ++m) {
        const int b = grp * 32 + m;
        const float* src = (v < 2) ? proj + ((size_t)b * 2 + v) * TD
                                   : pred + ((size_t)b * 4 + (v - 2)) * TD;
        x[m] = src[t];
    }
    #pragma unroll
    for (int m = 0; m < 32; ++m) rowbuf[m][t] = x[m];
    __syncthreads();

    // norms: 8 threads per row
    {
        const int row = t >> 3, l8 = t & 7;
        float ss = 0.f;
        #pragma unroll
        for (int n = 0; n < 32; ++n) { const float y = rowbuf[row][l8 + 8 * n]; ss += y * y; }
        ss += __shfl_xor(ss, 1, 64);
        ss += __shfl_xor(ss, 2, 64);
        ss += __shfl_xor(ss, 4, 64);
        if (l8 == 0) scales[row] = SQRT5 / fmaxf(sqrtf(ss), 1e-12f);
    }
    __syncthreads();

    // phase 2: transposed coalesced write: idx = (g*32 + col)*8 + e, g == m
    unsigned short* dst = pq2 + ((size_t)(v * 64 + grp) * 8192);
    const int col = t >> 3, e = t & 7;
    const float sc = scales[col];
    #pragma unroll
    for (int m = 0; m < 32; ++m) {
        const float y = rowbuf[col][m * 8 + e] * sc;
        const unsigned int bits = __float_as_uint(y);
        dst[m * 256 + t] = (unsigned short)((bits + 0x7FFFu + ((bits >> 16) & 1u)) >> 16);
    }
}

// ---------------------------------------------------------------------------
// Kernel 2: no staging LDS, no main-loop barriers. Block (rb, ch, j) computes
// rows b0..b0+31 x cols [ch*512,+512) for BOTH i (B-frag reused 2x). A/B frags
// loaded directly from L2-resident pq2 (coalesced 1KB/wave). Fixed-max m=5.
// grid (64, 4, 2) x 256 thr; ~230 VGPR -> 2 blocks/CU, 8 waves/CU.
// ---------------------------------------------------------------------------
__global__ __launch_bounds__(256, 2) void nnclr_main(const unsigned short* __restrict__ pq2,
                                                     float* __restrict__ sPart,  // [4][2048][4]
                                                     float* __restrict__ dPart)  // [4][2048][4]
{
    const int rb = blockIdx.x, ch = blockIdx.y, j = blockIdx.z;
    const int tid = threadIdx.x, lane = tid & 63, wave = tid >> 6;
    const int cl = lane & 31, hk = lane >> 5;
    const int b0 = rb * 32;

    const bf16x8* P = (const bf16x8*)pq2;               // granule-indexed
    // A granule: ((i*64 + rb)*32 + g)*32 + cl ; B granule: (((2+j)*64 + cg)*32 + g)*32 + cl
    bf16x8 aF0[16], aF1[16];
    #pragma unroll
    for (int ks = 0; ks < 16; ++ks) {
        const int g = 2 * ks + hk;
        aF0[ks] = P[((0 * 64 + rb) * 32 + g) * 32 + cl];
        aF1[ks] = P[((1 * 64 + rb) * 32 + g) * 32 + cl];
    }

    float sAcc0[16], sAcc1[16];
    #pragma unroll
    for (int r = 0; r < 16; ++r) { sAcc0[r] = 0.f; sAcc1[r] = 0.f; }
    float d0 = 0.f, d1 = 0.f;
    // lane's diagonal slot: holds C[row=cl][col=cl] iff hk==(cl>>2)&1, at r=rDiag
    const int  rDiag    = (cl & 3) + 4 * (cl >> 3);
    const bool laneDiag = (((cl >> 2) & 1) == hk);

    const bf16x8* Bbase = P + (size_t)(2 + j) * 64 * 32 * 32;
    const int cg0 = ch * 16 + wave * 4;                 // this wave's first col-group

    bf16x8 bq[4];
    #pragma unroll
    for (int k = 0; k < 4; ++k) bq[k] = Bbase[(cg0 * 32 + 2 * k + hk) * 32 + cl];

    #pragma unroll
    for (int cgl = 0; cgl < 4; ++cgl) {
        const int cgAbs = cg0 + cgl;
        f32x16 acc0, acc1;
        #pragma unroll
        for (int r = 0; r < 16; ++r) { acc0[r] = 0.f; acc1[r] = 0.f; }
        #pragma unroll
        for (int ks = 0; ks < 16; ++ks) {
            const bf16x8 b = bq[ks & 3];
            if (ks < 12)          bq[ks & 3] = Bbase[(cgAbs * 32 + 2 * (ks + 4) + hk) * 32 + cl];
            else if (cgl < 3)     bq[ks & 3] = Bbase[((cgAbs + 1) * 32 + 2 * (ks - 12) + hk) * 32 + cl];
            acc0 = __builtin_amdgcn_mfma_f32_32x32x16_bf16(aF0[ks], b, acc0, 0, 0, 0);
            acc1 = __builtin_amdgcn_mfma_f32_32x32x16_bf16(aF1[ks], b, acc1, 0, 0, 0);
        }
        // epilogue: fixed-max sum-of-exp + diag pick (static vector indexing)
        const bool diagCG = (cgAbs == rb);              // wave-uniform
        #pragma unroll
        for (int r = 0; r < 16; ++r) {
            const float v0 = acc0[r], v1 = acc1[r];
            sAcc0[r] += __expf(v0 - 5.0f);
            sAcc1[r] += __expf(v1 - 5.0f);
            if (diagCG) {
                const bool m = laneDiag && (r == rDiag);
                d0 += m ? v0 : 0.f;
                d1 += m ? v1 : 0.f;
            }
        }
    }

    // per-row col-sum: reduce over the 32 lanes of each hk half
    #pragma unroll
    for (int r = 0; r < 16; ++r) {
        float s0 = sAcc0[r], s1 = sAcc1[r];
        #pragma unroll
        for (int msk = 1; msk < 32; msk <<= 1) {
            s0 += __shfl_xor(s0, msk, 64);
            s1 += __shfl_xor(s1, msk, 64);
        }
        sAcc0[r] = s0; sAcc1[r] = s1;
    }

    __shared__ float sArr[2][4][32];
    __shared__ float dArr[2][4][32];
    if (cl == 0) {
        #pragma unroll
        for (int r = 0; r < 16; ++r) {
            const int rowl = (r & 3) + 8 * (r >> 2) + 4 * hk;
            sArr[0][wave][rowl] = sAcc0[r];
            sArr[1][wave][rowl] = sAcc1[r];
        }
    }
    if (laneDiag) { dArr[0][wave][cl] = d0; dArr[1][wave][cl] = d1; }
    __syncthreads();
    if (tid < 64) {
        const int i = tid >> 5, row = tid & 31;
        float s = 0.f, d = 0.f;
        #pragma unroll
        for (int w = 0; w < 4; ++w) { s += sArr[i][w][row]; d += dArr[i][w][row]; }
        const int pair = i * 2 + j;
        const int b = b0 + row;
        sPart[((size_t)pair * TB + b) * 4 + ch] = s;
        dPart[((size_t)pair * TB + b) * 4 + ch] = d;
    }
}

// ---------------------------------------------------------------------------
// Kernel 3: combine 4 chunks, lse - diag = 5 + ln(s) - d, reduce to 3 outputs.
// ---------------------------------------------------------------------------
__global__ __launch_bounds__(1024) void nnclr_final(const float* __restrict__ sPart,
                                                    const float* __restrict__ dPart,
                                                    float* __restrict__ out) {
    const int tid = threadIdx.x;
    float acc[4] = {0.f, 0.f, 0.f, 0.f};
    #pragma unroll
    for (int k = 0; k < 8; ++k) {
        const int row = tid + k * 1024;   // pair*2048 + b ; pair = k>>1 (constant)
        float s = 0.f, d = 0.f;
        #pragma unroll
        for (int c = 0; c < 4; ++c) { s += sPart[row * 4 + c]; d += dPart[row * 4 + c]; }
        acc[k >> 1] += 5.0f + logf(s) - d;
    }
    __shared__ float red[16][4];
    const int lane = tid & 63, wave = tid >> 6;
    #pragma unroll
    for (int p = 0; p < 4; ++p) {
        #pragma unroll
        for (int m = 1; m < 64; m <<= 1) acc[p] += __shfl_xor(acc[p], m, 64);
    }
    if (lane == 0) {
        #pragma unroll
        for (int p = 0; p < 4; ++p) red[wave][p] = acc[p];
    }
    __syncthreads();
    if (tid == 0) {
        float L[4];
        #pragma unroll
        for (int p = 0; p < 4; ++p) {
            float a = 0.f;
            for (int w = 0; w < 16; ++w) a += red[w][p];
            L[p] = a / (float)TB;         // mean over b
        }
        const float gs = L[1] + L[2];                 // L[0][1] + L[1][0]
        const float ls = L[0] + L[1] + L[2] + L[3];   // all four (Vl==Vg==2)
        out[0] = (gs + ls) / 6.0f;        // total
        out[1] = gs * 0.5f;               // global_loss
        out[2] = ls * 0.25f;              // local_loss
    }
}

extern "C" void kernel_launch(void* const* d_in, const int* in_sizes, int n_in,
                              void* d_out, int out_size, void* d_ws, size_t ws_size,
                              hipStream_t stream) {
    const float* projected = (const float*)d_in[0];   // [2048][2][256] f32
    const float* predicted = (const float*)d_in[1];   // [2048][4][256] f32

    unsigned short* pq2 = (unsigned short*)d_ws;                        // 4 MB bf16, fragment-ordered
    float* sPart = (float*)((char*)d_ws + 4u * 1024u * 1024u);          // 128 KB
    float* dPart = sPart + (size_t)4 * TB * 4;                          // 128 KB
    float* out = (float*)d_out;

    dim3 gprep(64, 4);
    nnclr_prep<<<gprep, 256, 0, stream>>>(projected, predicted, pq2);
    dim3 gmain(64, 4, 2);
    nnclr_main<<<gmain, 256, 0, stream>>>(pq2, sPart, dPart);
    nnclr_final<<<1, 1024, 0, stream>>>(sPart, dPart, out);
}

// Round 6
// 30.106 us; speedup vs baseline: 1.2298x; 1.0492x over previous
//
#include <hip/hip_runtime.h>
#include <hip/hip_bf16.h>
#include <stdint.h>

// Problem constants (fixed by reference): B=2048, D=256, Vg=2, Vt=4 (only j<2 used), T=0.2
#define TB 2048
#define TD 256

typedef __attribute__((ext_vector_type(8)))  short        bf16x8;
typedef __attribute__((ext_vector_type(16))) float        f32x16;

#define SQRT5 2.23606797749979f   // fold sqrt(1/T)=sqrt(5) into BOTH normalized operands

// ---------------------------------------------------------------------------
// Kernel 1: normalize rows, scale by sqrt(5), cast bf16, and write in MFMA
// fragment order: pq2[v][grp][g][col] of 16B granules, where v in {p_i0,p_i1,
// q_j0,q_j1}, grp = b>>5, col = b&31, g = k granule (k in [8g,8g+8)).
// One block per (grp, v): 32 rows staged in LDS, transposed write.
// ---------------------------------------------------------------------------
__global__ __launch_bounds__(256) void nnclr_prep(const float* __restrict__ proj,
                                                  const float* __restrict__ pred,
                                                  unsigned short* __restrict__ pq2) {
    const int grp = blockIdx.x;      // 0..63
    const int v   = blockIdx.y;      // 0..3
    const int t   = threadIdx.x;     // 0..255

    __shared__ float rowbuf[32][260];   // +4 pad: norm/phase-2 reads <=2-way conflict
    __shared__ float scales[32];

    // phase 1: bulk-load 32 rows (independent loads -> deep in flight)
    float x[32];
    #pragma unroll
    for (int m = 0; m < 32; ++m) {
        const int b = grp * 32 + m;
        const float* src = (v < 2) ? proj + ((size_t)b * 2 + v) * TD
                                   : pred + ((size_t)b * 4 + (v - 2)) * TD;
        x[m] = src[t];
    }
    #pragma unroll
    for (int m = 0; m < 32; ++m) rowbuf[m][t] = x[m];
    __syncthreads();

    // norms: 8 threads per row
    {
        const int row = t >> 3, l8 = t & 7;
        float ss = 0.f;
        #pragma unroll
        for (int n = 0; n < 32; ++n) { const float y = rowbuf[row][l8 + 8 * n]; ss += y * y; }
        ss += __shfl_xor(ss, 1, 64);
        ss += __shfl_xor(ss, 2, 64);
        ss += __shfl_xor(ss, 4, 64);
        if (l8 == 0) scales[row] = SQRT5 / fmaxf(sqrtf(ss), 1e-12f);
    }
    __syncthreads();

    // phase 2: transposed coalesced write: idx = (g*32 + col)*8 + e, g == m
    unsigned short* dst = pq2 + ((size_t)(v * 64 + grp) * 8192);
    const int col = t >> 3, e = t & 7;
    const float sc = scales[col];
    #pragma unroll
    for (int m = 0; m < 32; ++m) {
        const float y = rowbuf[col][m * 8 + e] * sc;
        const unsigned int bits = __float_as_uint(y);
        dst[m * 256 + t] = (unsigned short)((bits + 0x7FFFu + ((bits >> 16) & 1u)) >> 16);
    }
}

// ---------------------------------------------------------------------------
// Kernel 2: no staging LDS, no main-loop barriers. Block (rb, ch, j) computes
// rows b0..b0+31 x cols [ch*512,+512) for BOTH i (B-frag reused 2x). A/B frags
// loaded directly from L2-resident pq2 (coalesced 1KB/wave). 8-deep rolling B
// prefetch (issue-to-use >= L2 latency). Fixed-max m=5 sum-of-exp epilogue.
// grid (64, 4, 2) x 256 thr; ~240 VGPR -> 2 blocks/CU, 8 waves/CU.
// ---------------------------------------------------------------------------
__global__ __launch_bounds__(256, 2) void nnclr_main(const unsigned short* __restrict__ pq2,
                                                     float* __restrict__ sPart,  // [4][2048][4]
                                                     float* __restrict__ dPart)  // [4][2048][4]
{
    const int rb = blockIdx.x, ch = blockIdx.y, j = blockIdx.z;
    const int tid = threadIdx.x, lane = tid & 63, wave = tid >> 6;
    const int cl = lane & 31, hk = lane >> 5;
    const int b0 = rb * 32;

    const bf16x8* P = (const bf16x8*)pq2;               // granule-indexed
    // A granule: ((i*64 + rb)*32 + g)*32 + cl
    bf16x8 aF0[16], aF1[16];
    #pragma unroll
    for (int ks = 0; ks < 16; ++ks) {
        const int g = 2 * ks + hk;
        aF0[ks] = P[((0 * 64 + rb) * 32 + g) * 32 + cl];
        aF1[ks] = P[((1 * 64 + rb) * 32 + g) * 32 + cl];
    }

    float sAcc0[16], sAcc1[16];
    #pragma unroll
    for (int r = 0; r < 16; ++r) { sAcc0[r] = 0.f; sAcc1[r] = 0.f; }
    float d0 = 0.f, d1 = 0.f;
    // lane's diagonal slot: holds C[row=cl][col=cl] iff hk==(cl>>2)&1, at r=rDiag
    const int  rDiag    = (cl & 3) + 4 * (cl >> 3);
    const bool laneDiag = (((cl >> 2) & 1) == hk);

    const bf16x8* Bbase = P + (size_t)(2 + j) * 64 * 32 * 32;
    const int cg0 = ch * 16 + wave * 4;                 // this wave's first col-group

    // 8-deep rolling prefetch of the flat 64-granule B stream
    bf16x8 bq[8];
    #pragma unroll
    for (int k = 0; k < 8; ++k) bq[k] = Bbase[(cg0 * 32 + 2 * k + hk) * 32 + cl];

    #pragma unroll
    for (int cgl = 0; cgl < 4; ++cgl) {
        const int cg = cg0 + cgl;
        f32x16 acc0, acc1;
        #pragma unroll
        for (int r = 0; r < 16; ++r) { acc0[r] = 0.f; acc1[r] = 0.f; }
        #pragma unroll
        for (int ks = 0; ks < 16; ++ks) {
            const bf16x8 b = bq[ks & 7];
            if (ks < 8)        bq[ks & 7] = Bbase[(cg * 32 + 2 * (ks + 8) + hk) * 32 + cl];
            else if (cgl < 3)  bq[ks & 7] = Bbase[((cg + 1) * 32 + 2 * (ks - 8) + hk) * 32 + cl];
            acc0 = __builtin_amdgcn_mfma_f32_32x32x16_bf16(aF0[ks], b, acc0, 0, 0, 0);
            acc1 = __builtin_amdgcn_mfma_f32_32x32x16_bf16(aF1[ks], b, acc1, 0, 0, 0);
        }
        // epilogue: fixed-max sum-of-exp + diag pick (static vector indexing)
        const bool diagCG = (cg == rb);                 // wave-uniform
        #pragma unroll
        for (int r = 0; r < 16; ++r) {
            const float v0 = acc0[r], v1 = acc1[r];
            sAcc0[r] += __expf(v0 - 5.0f);
            sAcc1[r] += __expf(v1 - 5.0f);
            if (diagCG) {
                const bool m = laneDiag && (r == rDiag);
                d0 += m ? v0 : 0.f;
                d1 += m ? v1 : 0.f;
            }
        }
    }

    // per-row col-sum: reduce over the 32 lanes of each hk half
    #pragma unroll
    for (int r = 0; r < 16; ++r) {
        float s0 = sAcc0[r], s1 = sAcc1[r];
        #pragma unroll
        for (int msk = 1; msk < 32; msk <<= 1) {
            s0 += __shfl_xor(s0, msk, 64);
            s1 += __shfl_xor(s1, msk, 64);
        }
        sAcc0[r] = s0; sAcc1[r] = s1;
    }

    __shared__ float sArr[2][4][32];
    __shared__ float dArr[2][4][32];
    if (cl == 0) {
        #pragma unroll
        for (int r = 0; r < 16; ++r) {
            const int rowl = (r & 3) + 8 * (r >> 2) + 4 * hk;
            sArr[0][wave][rowl] = sAcc0[r];
            sArr[1][wave][rowl] = sAcc1[r];
        }
    }
    if (laneDiag) { dArr[0][wave][cl] = d0; dArr[1][wave][cl] = d1; }
    __syncthreads();
    if (tid < 64) {
        const int i = tid >> 5, row = tid & 31;
        float s = 0.f, d = 0.f;
        #pragma unroll
        for (int w = 0; w < 4; ++w) { s += sArr[i][w][row]; d += dArr[i][w][row]; }
        const int pair = i * 2 + j;
        const int b = b0 + row;
        sPart[((size_t)pair * TB + b) * 4 + ch] = s;
        dPart[((size_t)pair * TB + b) * 4 + ch] = d;
    }
}

// ---------------------------------------------------------------------------
// Kernel 3a: per (pair,row) combine 4 chunks, L = 5 + ln(s) - d; block-reduce.
// 32 blocks x 256 thr; block b covers 256 rows of pair (b>>3). Coalesced
// float4 reads spread over 32 CUs (vs single-block serialization before).
// ---------------------------------------------------------------------------
__global__ __launch_bounds__(256) void nnclr_final1(const float* __restrict__ sPart,
                                                    const float* __restrict__ dPart,
                                                    float* __restrict__ Lpart) {
    const int tid = threadIdx.x;
    const int item = blockIdx.x * 256 + tid;            // pair*2048 + row
    const float4 sv = ((const float4*)sPart)[item];
    const float4 dv = ((const float4*)dPart)[item];
    const float s = (sv.x + sv.y) + (sv.z + sv.w);
    const float d = (dv.x + dv.y) + (dv.z + dv.w);
    float L = 5.0f + logf(s) - d;
    #pragma unroll
    for (int m = 1; m < 64; m <<= 1) L += __shfl_xor(L, m, 64);
    __shared__ float wsum[4];
    const int lane = tid & 63, wave = tid >> 6;
    if (lane == 0) wsum[wave] = L;
    __syncthreads();
    if (tid == 0) Lpart[blockIdx.x] = (wsum[0] + wsum[1]) + (wsum[2] + wsum[3]);
}

// ---------------------------------------------------------------------------
// Kernel 3b: 1 wave: combine 32 block partials (8 per pair) -> 3 outputs.
// ---------------------------------------------------------------------------
__global__ __launch_bounds__(64) void nnclr_final2(const float* __restrict__ Lpart,
                                                   float* __restrict__ out) {
    const int t = threadIdx.x;
    float v = (t < 32) ? Lpart[t] : 0.f;
    v += __shfl_xor(v, 1, 64);
    v += __shfl_xor(v, 2, 64);
    v += __shfl_xor(v, 4, 64);                          // lane 8p holds pair-p sum
    const float L0 = __shfl(v, 0, 64)  * (1.0f / TB);
    const float L1 = __shfl(v, 8, 64)  * (1.0f / TB);
    const float L2 = __shfl(v, 16, 64) * (1.0f / TB);
    const float L3 = __shfl(v, 24, 64) * (1.0f / TB);
    if (t == 0) {
        const float gs = L1 + L2;                       // L[0][1] + L[1][0]
        const float ls = L0 + L1 + L2 + L3;             // all four (Vl==Vg==2)
        out[0] = (gs + ls) / 6.0f;                      // total
        out[1] = gs * 0.5f;                             // global_loss
        out[2] = ls * 0.25f;                            // local_loss
    }
}

extern "C" void kernel_launch(void* const* d_in, const int* in_sizes, int n_in,
                              void* d_out, int out_size, void* d_ws, size_t ws_size,
                              hipStream_t stream) {
    const float* projected = (const float*)d_in[0];   // [2048][2][256] f32
    const float* predicted = (const float*)d_in[1];   // [2048][4][256] f32

    unsigned short* pq2 = (unsigned short*)d_ws;                        // 4 MB bf16, fragment-ordered
    float* sPart = (float*)((char*)d_ws + 4u * 1024u * 1024u);          // 128 KB
    float* dPart = sPart + (size_t)4 * TB * 4;                          // 128 KB
    float* Lpart = dPart + (size_t)4 * TB * 4;                          // 128 B
    float* out = (float*)d_out;

    dim3 gprep(64, 4);
    nnclr_prep<<<gprep, 256, 0, stream>>>(projected, predicted, pq2);
    dim3 gmain(64, 4, 2);
    nnclr_main<<<gmain, 256, 0, stream>>>(pq2, sPart, dPart);
    nnclr_final1<<<32, 256, 0, stream>>>(sPart, dPart, Lpart);
    nnclr_final2<<<1, 64, 0, stream>>>(Lpart, out);
}

// Round 8
// 27.690 us; speedup vs baseline: 1.3371x; 1.0873x over previous
//
#include <hip/hip_runtime.h>
#include <hip/hip_bf16.h>
#include <hip/hip_fp8.h>
#include <stdint.h>

// Problem constants (fixed by reference): B=2048, D=256, Vg=2, Vt=4 (only j<2 used), T=0.2
#define TB 2048
#define TD 256

typedef long long                                         fp8x8;   // 8 fp8 = 2 VGPR
typedef __attribute__((ext_vector_type(16))) float        f32x16;

#define SQRT5 2.23606797749979f   // fold sqrt(1/T)=sqrt(5) into BOTH normalized operands

// ---------------------------------------------------------------------------
// Kernel 1: normalize rows, scale by sqrt(5), cast fp8-e4m3 (OCP), write in
// MFMA fragment order: pq2[v][grp][g][col] of 8B granules (granule g holds
// k in [8g,8g+8) for batch-col `col`). v in {p_i0,p_i1,q_j0,q_j1}.
// ---------------------------------------------------------------------------
__global__ __launch_bounds__(256) void nnclr_prep(const float* __restrict__ proj,
                                                  const float* __restrict__ pred,
                                                  unsigned char* __restrict__ pq2) {
    const int grp = blockIdx.x;      // 0..63
    const int v   = blockIdx.y;      // 0..3
    const int t   = threadIdx.x;     // 0..255

    __shared__ float rowbuf[32][261];   // pad 261 (gcd(5,32)=1): <=2-way conflicts
    __shared__ float scales[32];

    // phase 1: bulk-load 32 rows (independent loads -> deep in flight)
    float x[32];
    #pragma unroll
    for (int m = 0; m < 32; ++m) {
        const int b = grp * 32 + m;
        const float* src = (v < 2) ? proj + ((size_t)b * 2 + v) * TD
                                   : pred + ((size_t)b * 4 + (v - 2)) * TD;
        x[m] = src[t];
    }
    #pragma unroll
    for (int m = 0; m < 32; ++m) rowbuf[m][t] = x[m];
    __syncthreads();

    // norms: 8 threads per row
    {
        const int row = t >> 3, l8 = t & 7;
        float ss = 0.f;
        #pragma unroll
        for (int n = 0; n < 32; ++n) { const float y = rowbuf[row][l8 + 8 * n]; ss += y * y; }
        ss += __shfl_xor(ss, 1, 64);
        ss += __shfl_xor(ss, 2, 64);
        ss += __shfl_xor(ss, 4, 64);
        if (l8 == 0) scales[row] = SQRT5 / fmaxf(sqrtf(ss), 1e-12f);
    }
    __syncthreads();

    // phase 2: pack 4 fp8/thread/iter, coalesced uint stores.
    // byte addr within (v,grp) tile: (g*32 + col)*8 + e ; here g==m, e = 4*e4+i.
    unsigned int* dst32 = (unsigned int*)(pq2 + (size_t)(v * 64 + grp) * 8192);
    #pragma unroll
    for (int it = 0; it < 8; ++it) {
        const int u   = it * 256 + t;     // uint index, 0..2047
        const int m   = u >> 6;
        const int col = (u >> 1) & 31;
        const int e4  = u & 1;
        const float sc = scales[col];
        unsigned int w = 0;
        #pragma unroll
        for (int i = 0; i < 4; ++i) {
            const float y = rowbuf[col][m * 8 + 4 * e4 + i] * sc;
            const __hip_fp8_e4m3 f8(y);
            w |= ((unsigned int)f8.__x) << (8 * i);
        }
        dst32[u] = w;
    }
}

// ---------------------------------------------------------------------------
// Kernel 2: fp8 MFMA, no staging LDS, no main-loop barriers. Block (rb,ch,j):
// rows b0..b0+31 x cols [ch*512,+512) for BOTH i (B-frag reused 2x). A/B frags
// direct from L2-resident pq2 (512B/wave-load). 8-deep rolling B prefetch.
// Fixed-max m=5 sum-of-exp epilogue. ~165 VGPR -> no spill, 8 waves/CU.
// ---------------------------------------------------------------------------
__global__ __launch_bounds__(256, 2) void nnclr_main(const unsigned char* __restrict__ pq2,
                                                     float* __restrict__ sPart,  // [4][2048][4]
                                                     float* __restrict__ dPart)  // [4][2048][4]
{
    const int rb = blockIdx.x, ch = blockIdx.y, j = blockIdx.z;
    const int tid = threadIdx.x, lane = tid & 63, wave = tid >> 6;
    const int cl = lane & 31, hk = lane >> 5;
    const int b0 = rb * 32;

    const fp8x8* P = (const fp8x8*)pq2;                 // granule-indexed (8B)
    // A granule: ((i*64 + rb)*32 + g)*32 + cl , g = 2*ks + hk
    fp8x8 aF0[16], aF1[16];
    #pragma unroll
    for (int ks = 0; ks < 16; ++ks) {
        const int g = 2 * ks + hk;
        aF0[ks] = P[((0 * 64 + rb) * 32 + g) * 32 + cl];
        aF1[ks] = P[((1 * 64 + rb) * 32 + g) * 32 + cl];
    }

    float sAcc0[16], sAcc1[16];
    #pragma unroll
    for (int r = 0; r < 16; ++r) { sAcc0[r] = 0.f; sAcc1[r] = 0.f; }
    float d0 = 0.f, d1 = 0.f;
    // lane's diagonal slot: holds C[row=cl][col=cl] iff hk==(cl>>2)&1, at r=rDiag
    const int  rDiag    = (cl & 3) + 4 * (cl >> 3);
    const bool laneDiag = (((cl >> 2) & 1) == hk);

    const fp8x8* Bbase = P + (size_t)(2 + j) * 64 * 32 * 32;
    const int cg0 = ch * 16 + wave * 4;                 // this wave's first col-group

    // 8-deep rolling prefetch of the flat 64-granule B stream
    fp8x8 bq[8];
    #pragma unroll
    for (int k = 0; k < 8; ++k) bq[k] = Bbase[(cg0 * 32 + 2 * k + hk) * 32 + cl];

    #pragma unroll
    for (int cgl = 0; cgl < 4; ++cgl) {
        const int cg = cg0 + cgl;
        f32x16 acc0, acc1;
        #pragma unroll
        for (int r = 0; r < 16; ++r) { acc0[r] = 0.f; acc1[r] = 0.f; }
        #pragma unroll
        for (int ks = 0; ks < 16; ++ks) {
            const fp8x8 b = bq[ks & 7];
            if (ks < 8)        bq[ks & 7] = Bbase[(cg * 32 + 2 * (ks + 8) + hk) * 32 + cl];
            else if (cgl < 3)  bq[ks & 7] = Bbase[((cg + 1) * 32 + 2 * (ks - 8) + hk) * 32 + cl];
            acc0 = __builtin_amdgcn_mfma_f32_32x32x16_fp8_fp8(aF0[ks], b, acc0, 0, 0, 0);
            acc1 = __builtin_amdgcn_mfma_f32_32x32x16_fp8_fp8(aF1[ks], b, acc1, 0, 0, 0);
        }
        // epilogue: fixed-max sum-of-exp + diag pick (static vector indexing)
        const bool diagCG = (cg == rb);                 // wave-uniform
        #pragma unroll
        for (int r = 0; r < 16; ++r) {
            const float v0 = acc0[r], v1 = acc1[r];
            sAcc0[r] += __expf(v0 - 5.0f);
            sAcc1[r] += __expf(v1 - 5.0f);
            if (diagCG) {
                const bool m = laneDiag && (r == rDiag);
                d0 += m ? v0 : 0.f;
                d1 += m ? v1 : 0.f;
            }
        }
    }

    // per-row col-sum: reduce over the 32 lanes of each hk half
    #pragma unroll
    for (int r = 0; r < 16; ++r) {
        float s0 = sAcc0[r], s1 = sAcc1[r];
        #pragma unroll
        for (int msk = 1; msk < 32; msk <<= 1) {
            s0 += __shfl_xor(s0, msk, 64);
            s1 += __shfl_xor(s1, msk, 64);
        }
        sAcc0[r] = s0; sAcc1[r] = s1;
    }

    __shared__ float sArr[2][4][32];
    __shared__ float dArr[2][4][32];
    if (cl == 0) {
        #pragma unroll
        for (int r = 0; r < 16; ++r) {
            const int rowl = (r & 3) + 8 * (r >> 2) + 4 * hk;
            sArr[0][wave][rowl] = sAcc0[r];
            sArr[1][wave][rowl] = sAcc1[r];
        }
    }
    if (laneDiag) { dArr[0][wave][cl] = d0; dArr[1][wave][cl] = d1; }
    __syncthreads();
    if (tid < 64) {
        const int i = tid >> 5, row = tid & 31;
        float s = 0.f, d = 0.f;
        #pragma unroll
        for (int w = 0; w < 4; ++w) { s += sArr[i][w][row]; d += dArr[i][w][row]; }
        const int pair = i * 2 + j;
        const int b = b0 + row;
        sPart[((size_t)pair * TB + b) * 4 + ch] = s;
        dPart[((size_t)pair * TB + b) * 4 + ch] = d;
    }
}

// ---------------------------------------------------------------------------
// Kernel 3a: per (pair,row) combine 4 chunks, L = 5 + ln(s) - d; block-reduce.
// ---------------------------------------------------------------------------
__global__ __launch_bounds__(256) void nnclr_final1(const float* __restrict__ sPart,
                                                    const float* __restrict__ dPart,
                                                    float* __restrict__ Lpart) {
    const int tid = threadIdx.x;
    const int item = blockIdx.x * 256 + tid;            // pair*2048 + row
    const float4 sv = ((const float4*)sPart)[item];
    const float4 dv = ((const float4*)dPart)[item];
    const float s = (sv.x + sv.y) + (sv.z + sv.w);
    const float d = (dv.x + dv.y) + (dv.z + dv.w);
    float L = 5.0f + logf(s) - d;
    #pragma unroll
    for (int m = 1; m < 64; m <<= 1) L += __shfl_xor(L, m, 64);
    __shared__ float wsum[4];
    const int lane = tid & 63, wave = tid >> 6;
    if (lane == 0) wsum[wave] = L;
    __syncthreads();
    if (tid == 0) Lpart[blockIdx.x] = (wsum[0] + wsum[1]) + (wsum[2] + wsum[3]);
}

// ---------------------------------------------------------------------------
// Kernel 3b: 1 wave: combine 32 block partials (8 per pair) -> 3 outputs.
// ---------------------------------------------------------------------------
__global__ __launch_bounds__(64) void nnclr_final2(const float* __restrict__ Lpart,
                                                   float* __restrict__ out) {
    const int t = threadIdx.x;
    float v = (t < 32) ? Lpart[t] : 0.f;
    v += __shfl_xor(v, 1, 64);
    v += __shfl_xor(v, 2, 64);
    v += __shfl_xor(v, 4, 64);                          // lane 8p holds pair-p sum
    const float L0 = __shfl(v, 0, 64)  * (1.0f / TB);
    const float L1 = __shfl(v, 8, 64)  * (1.0f / TB);
    const float L2 = __shfl(v, 16, 64) * (1.0f / TB);
    const float L3 = __shfl(v, 24, 64) * (1.0f / TB);
    if (t == 0) {
        const float gs = L1 + L2;                       // L[0][1] + L[1][0]
        const float ls = L0 + L1 + L2 + L3;             // all four (Vl==Vg==2)
        out[0] = (gs + ls) / 6.0f;                      // total
        out[1] = gs * 0.5f;                             // global_loss
        out[2] = ls * 0.25f;                            // local_loss
    }
}

extern "C" void kernel_launch(void* const* d_in, const int* in_sizes, int n_in,
                              void* d_out, int out_size, void* d_ws, size_t ws_size,
                              hipStream_t stream) {
    const float* projected = (const float*)d_in[0];   // [2048][2][256] f32
    const float* predicted = (const float*)d_in[1];   // [2048][4][256] f32

    unsigned char* pq2 = (unsigned char*)d_ws;                          // 2 MB fp8, fragment-ordered
    float* sPart = (float*)((char*)d_ws + 4u * 1024u * 1024u);          // 128 KB
    float* dPart = sPart + (size_t)4 * TB * 4;                          // 128 KB
    float* Lpart = dPart + (size_t)4 * TB * 4;                          // 128 B
    float* out = (float*)d_out;

    dim3 gprep(64, 4);
    nnclr_prep<<<gprep, 256, 0, stream>>>(projected, predicted, pq2);
    dim3 gmain(64, 4, 2);
    nnclr_main<<<gmain, 256, 0, stream>>>(pq2, sPart, dPart);
    nnclr_final1<<<32, 256, 0, stream>>>(sPart, dPart, Lpart);
    nnclr_final2<<<1, 64, 0, stream>>>(Lpart, out);
}